// Round 15
// baseline (24.634 us; speedup 1.0000x reference)
//
#include <hip/hip_runtime.h>
#include <math.h>

#define RES     32
#define GCELLS  (RES * RES * RES)       // 32768
#define NPTS    32768
#define BATCH   64
#define NPLANES 3
#define EPS_PD  1e-6f
#define WREG_F  25.0f

#define NB      512                     // sym blocks: 2 per CU (32 waves = max)
#define NT      1024
#define NWAVES  (NT / 64)

#define PACK_BLOCKS 2048
#define PACKED_BYTES ((size_t)BATCH * GCELLS * 2)    // 4 MiB (u16/cell)

typedef float          f4 __attribute__((ext_vector_type(4)));
typedef unsigned int   u32;
typedef unsigned short u16;
typedef u32            u4 __attribute__((ext_vector_type(4)));
typedef u32            u2 __attribute__((ext_vector_type(2)));

// ---------------------------------------------------------------------------
// helpers
// ---------------------------------------------------------------------------
__device__ __forceinline__ u32 quant_cell4(float x, float y, float z, float v) {
    // 4-bit each: u = round_half_up((c+0.5)*15) = floor(c*15 + 8); v: round(v*15)
    const u32 ux = (u32)fmaf(x, 15.0f, 8.0f);
    const u32 uy = (u32)fmaf(y, 15.0f, 8.0f);
    const u32 uz = (u32)fmaf(z, 15.0f, 8.0f);
    const u32 uv = (u32)fmaf(v, 15.0f, 0.5f);
    return ux | (uy << 4) | (uz << 8) | (uv << 12);
}

__device__ __forceinline__ float reg_term(const float* __restrict__ planes, int b) {
    float nv[3][3];
    #pragma unroll
    for (int p = 0; p < NPLANES; ++p) {
        const float nxv = planes[((p * BATCH + b) << 2) + 0];
        const float nyv = planes[((p * BATCH + b) << 2) + 1];
        const float nzv = planes[((p * BATCH + b) << 2) + 2];
        float nrm = fmaxf(sqrtf(nxv*nxv + nyv*nyv + nzv*nzv), 1e-12f);
        nv[p][0] = nxv / nrm; nv[p][1] = nyv / nrm; nv[p][2] = nzv / nrm;
    }
    float r = 0.0f;
    #pragma unroll
    for (int i = 0; i < 3; ++i)
        #pragma unroll
        for (int j = 0; j < 3; ++j) {
            const float m = nv[i][j] * nv[j][i] - (i == j ? 1.0f : 0.0f);
            r += m * m;
        }
    return r;
}

// ---------------------------------------------------------------------------
// Kernel 1: quantize (aux.xyz, vox) -> u16 table (4 bits/field), XCD-swizzled.
// Block 0 initializes out[0] with the regularizer (ordered before sym by the
// kernel boundary; rewritten every replay).
// ---------------------------------------------------------------------------
__device__ __forceinline__ int swizzle_chunk(int bid) {
    return (bid & 7) * (PACK_BLOCKS / 8) + (bid >> 3);
}

__global__ __launch_bounds__(256) void pack_u16_kernel(
    const float* __restrict__ aux,
    const float* __restrict__ vox,
    const float* __restrict__ planes,
    u16* __restrict__ packed,
    float* __restrict__ out)
{
    if (blockIdx.x == 0) {
        __shared__ float rsum[1];
        if (threadIdx.x == 0) rsum[0] = 0.0f;
        __syncthreads();
        if (threadIdx.x < 64) {
            float r = reg_term(planes, threadIdx.x) * (WREG_F / (float)BATCH);
            #pragma unroll
            for (int off = 32; off > 0; off >>= 1)
                r += __shfl_down(r, off);
            if (threadIdx.x == 0) rsum[0] = r;
        }
        __syncthreads();
        if (threadIdx.x == 0) out[0] = rsum[0];
    }

    const int chunk = swizzle_chunk(blockIdx.x);
    const int i = chunk * 256 + threadIdx.x;        // group of 4 cells

    const f4* a4 = (const f4*)aux + (size_t)i * 3;
    const f4 a = a4[0];
    const f4 b = a4[1];
    const f4 c = a4[2];
    const f4 v = ((const f4*)vox)[i];

    const u32 c0 = quant_cell4(a.x, a.y, a.z, v.x);
    const u32 c1 = quant_cell4(a.w, b.x, b.y, v.y);
    const u32 c2 = quant_cell4(b.z, b.w, c.x, v.z);
    const u32 c3 = quant_cell4(c.y, c.z, c.w, v.w);

    u2 o;
    o[0] = c0 | (c1 << 16);
    o[1] = c2 | (c3 << 16);
    *((u2*)packed + i) = o;            // 8-B store: table stays in this L2
}

// ---------------------------------------------------------------------------
// Kernel 2: 512 blocks (2/CU = 32 waves/CU, HW max). Table staged via
// global_load_lds DMA (4 x 16 B/thread, linear layout -- no VGPR roundtrip,
// overlaps the pc loads in flight). 4 pts/thread compiler-interleaved gather;
// one fp32 atomicAdd per block into out[0].
// ---------------------------------------------------------------------------
__global__ __launch_bounds__(NT, 8) void sym_lds_kernel(
    const float* __restrict__ pc,      // (B, N, 3)
    const u16* __restrict__ packed,    // (B*G) u16
    const float* __restrict__ planes,  // (3, B, 4)
    float* __restrict__ out)
{
    __shared__ u16   tab[GCELLS];      // 64 KiB
    __shared__ float wsum[NWAVES];

    const int t    = threadIdx.x;
    const int blk  = blockIdx.x;
    const int xcd  = blk & 7;
    const int slot = blk >> 3;                 // 0..63 on this XCD
    const int b    = xcd * 8 + (slot >> 3);    // batch (8 blocks/batch, same XCD)
    const int c    = slot & 7;                 // eighth of the batch's points

    // ---- pc loads first: in flight alongside the staging DMA ----
    const f4* pc4 = (const f4*)pc
                  + (((size_t)(b * NPTS + c * 4096) * 3) >> 2)
                  + (size_t)t * 3;
    f4 A[3];
    #pragma unroll
    for (int i = 0; i < 3; ++i) A[i] = pc4[i];

    // ---- stage 64 KB table via direct global->LDS DMA (16 B/lane, linear) ----
    {
        const char* gb = (const char*)(packed + (size_t)b * GCELLS);
        char*       lb = (char*)tab;
        #pragma unroll
        for (int i = 0; i < 4; ++i) {
            const u32 off = ((u32)i * NT + t) * 16u;
            __builtin_amdgcn_global_load_lds(
                (const __attribute__((address_space(1))) void*)(gb + off),
                (__attribute__((address_space(3))) void*)(lb + off),
                16, 0, 0);
        }
    }

    // ---- block-uniform plane constants (sc folded into normals) ----
    float nx[3], ny[3], nz[3], dd[3], mx[3], my[3], mz[3];
    #pragma unroll
    for (int pl = 0; pl < NPLANES; ++pl) {
        const float* P = planes + ((pl * BATCH + b) << 2);
        nx[pl] = P[0]; ny[pl] = P[1]; nz[pl] = P[2]; dd[pl] = P[3];
        const float sc = 2.0f / (nx[pl]*nx[pl] + ny[pl]*ny[pl] + nz[pl]*nz[pl]);
        mx[pl] = sc * nx[pl]; my[pl] = sc * ny[pl]; mz[pl] = sc * nz[pl];
    }

    __syncthreads();                   // compiler drains vmcnt before barrier

    const float* f = (const float*)A;
    const float SHIFT = 0.5f + EPS_PD;         // fold +0.5 and +eps into q
    const float IOFF  = -32.0f * EPS_PD;       // undo eps in the index path
    const float INV15 = 1.0f / 15.0f;

    // ---- gather loop: 4 points x 3 planes, compiler-interleaved ----
    float acc = 0.0f;
    #pragma unroll
    for (int p = 0; p < 4; ++p) {
        const float px = f[3*p], py = f[3*p+1], pz = f[3*p+2];
        const float pxs = px + SHIFT, pys = py + SHIFT, pzs = pz + SHIFT;
        #pragma unroll
        for (int pl = 0; pl < NPLANES; ++pl) {
            // tt' = dot(p,n) + d  (3 fma); q = p - tt' * (sc*n)
            const float tt  = fmaf(pz, nz[pl], fmaf(py, ny[pl],
                              fmaf(px, nx[pl], dd[pl])));
            const float qxs = fmaf(-tt, mx[pl], pxs);   // qx + 0.5 + eps
            const float qys = fmaf(-tt, my[pl], pys);
            const float qzs = fmaf(-tt, mz[pl], pzs);
            int ix = (int)fmaf(qxs, 32.0f, IOFF);
            int iy = (int)fmaf(qys, 32.0f, IOFF);
            int iz = (int)fmaf(qzs, 32.0f, IOFF);
            ix = min(max(ix, 0), RES - 1);
            iy = min(max(iy, 0), RES - 1);
            iz = min(max(iz, 0), RES - 1);
            const u32 g    = ((u32)ix << 10) + ((u32)iy << 5) + (u32)iz;
            const u32 cell = (u32)tab[g];
            const float dx = fmaf((float)(cell & 15u),        -INV15, qxs);
            const float dy = fmaf((float)((cell >> 4) & 15u), -INV15, qys);
            const float dz = fmaf((float)((cell >> 8) & 15u), -INV15, qzs);
            const float w  = fmaf((float)(cell >> 12),        -INV15, 1.0f);
            acc = fmaf(__builtin_amdgcn_sqrtf(dx*dx + dy*dy + dz*dz), w, acc);
        }
    }

    // ---- block reduce, then one atomicAdd into out[0] ----
    #pragma unroll
    for (int off = 32; off > 0; off >>= 1)
        acc += __shfl_down(acc, off);
    if ((t & 63) == 0) wsum[t >> 6] = acc;
    __syncthreads();
    if (t == 0) {
        float s = 0.0f;
        #pragma unroll
        for (int w = 0; w < NWAVES; ++w) s += wsum[w];
        atomicAdd(out, s * (1.0f / (float)BATCH));
    }
}

// ---------------------------------------------------------------------------
// Fallback (ws too small): direct fp32 gathers + separate finalize.
// ---------------------------------------------------------------------------
__global__ __launch_bounds__(256) void finalize_fb_kernel(
    const float* __restrict__ part, int n_part,
    const float* __restrict__ planes,
    float* __restrict__ out)
{
    __shared__ float sdata[256];

    float s = 0.0f;
    for (int i = threadIdx.x; i < n_part; i += 256)
        s += part[i];

    float r = 0.0f;
    if (threadIdx.x < BATCH)
        r = reg_term(planes, threadIdx.x);

    float val = s * (1.0f / (float)BATCH) + r * (WREG_F / (float)BATCH);

    sdata[threadIdx.x] = val;
    __syncthreads();
    #pragma unroll
    for (int off = 128; off > 0; off >>= 1) {
        if (threadIdx.x < off) sdata[threadIdx.x] += sdata[threadIdx.x + off];
        __syncthreads();
    }
    if (threadIdx.x == 0) out[0] = sdata[0];
}

__global__ __launch_bounds__(256) void sym_fallback_kernel(
    const float* __restrict__ pc,
    const float* __restrict__ aux,
    const float* __restrict__ vox,
    const float* __restrict__ planes,
    float* __restrict__ part)
{
    const int chunk = swizzle_chunk(blockIdx.x);
    const int b  = chunk >> 5;
    const int cb = chunk & 31;

    float nx[3], ny[3], nz[3], dd[3], sc[3];
    #pragma unroll
    for (int pl = 0; pl < NPLANES; ++pl) {
        const float* P = planes + ((pl * BATCH + b) << 2);
        nx[pl] = P[0]; ny[pl] = P[1]; nz[pl] = P[2]; dd[pl] = P[3];
        sc[pl] = 2.0f / (nx[pl]*nx[pl] + ny[pl]*ny[pl] + nz[pl]*nz[pl]);
    }

    const int p0 = b * NPTS + cb * 1024 + threadIdx.x * 4;
    const f4* pc4 = (const f4*)pc + (size_t)(p0 >> 2) * 3;
    const f4 A  = pc4[0];
    const f4 Bv = pc4[1];
    const f4 C  = pc4[2];

    const float px[4] = {A.x, A.w, Bv.z, C.y};
    const float py[4] = {A.y, Bv.x, Bv.w, C.z};
    const float pz[4] = {A.z, Bv.y, C.x, C.w};

    float acc = 0.0f;
    #pragma unroll
    for (int pt = 0; pt < 4; ++pt) {
        #pragma unroll
        for (int pl = 0; pl < NPLANES; ++pl) {
            const float tt = (px[pt]*nx[pl] + py[pt]*ny[pl] + pz[pt]*nz[pl]
                              + dd[pl]) * sc[pl];
            const float qx = px[pt] - tt * nx[pl];
            const float qy = py[pt] - tt * ny[pl];
            const float qz = pz[pt] - tt * nz[pl];
            int ix = (int)((qx + 0.5f) * (float)RES);
            int iy = (int)((qy + 0.5f) * (float)RES);
            int iz = (int)((qz + 0.5f) * (float)RES);
            ix = min(RES - 1, max(0, ix));
            iy = min(RES - 1, max(0, iy));
            iz = min(RES - 1, max(0, iz));
            const int gi = b * GCELLS + (ix << 10) + (iy << 5) + iz;
            const float v  = vox[gi];
            const float dx = qx - aux[gi*3+0] + EPS_PD;
            const float dy = qy - aux[gi*3+1] + EPS_PD;
            const float dz = qz - aux[gi*3+2] + EPS_PD;
            acc += sqrtf(dx*dx + dy*dy + dz*dz) * (1.0f - v);
        }
    }

    #pragma unroll
    for (int off = 32; off > 0; off >>= 1)
        acc += __shfl_down(acc, off);

    __shared__ float ws[4];
    if ((threadIdx.x & 63) == 0) ws[threadIdx.x >> 6] = acc;
    __syncthreads();
    if (threadIdx.x == 0)
        part[blockIdx.x] = ws[0] + ws[1] + ws[2] + ws[3];
}

// ---------------------------------------------------------------------------
extern "C" void kernel_launch(void* const* d_in, const int* in_sizes, int n_in,
                              void* d_out, int out_size, void* d_ws, size_t ws_size,
                              hipStream_t stream)
{
    const float* pc     = (const float*)d_in[0];
    const float* aux    = (const float*)d_in[1];
    const float* vox    = (const float*)d_in[2];
    const float* planes = (const float*)d_in[3];
    float* out = (float*)d_out;

    if (ws_size >= PACKED_BYTES) {
        u16* packed = (u16*)d_ws;
        pack_u16_kernel<<<PACK_BLOCKS, 256, 0, stream>>>(aux, vox, planes, packed, out);
        sym_lds_kernel<<<NB, NT, 0, stream>>>(pc, packed, planes, out);
    } else {
        float* part = (float*)d_ws;
        sym_fallback_kernel<<<PACK_BLOCKS, 256, 0, stream>>>(pc, aux, vox, planes, part);
        finalize_fb_kernel<<<1, 256, 0, stream>>>(part, PACK_BLOCKS, planes, out);
    }
}

// Round 16
// 23.977 us; speedup vs baseline: 1.0274x; 1.0274x over previous
//
#include <hip/hip_runtime.h>
#include <math.h>

#define RES     32
#define GCELLS  (RES * RES * RES)       // 32768
#define NPTS    32768
#define BATCH   64
#define NPLANES 3
#define EPS_PD  1e-6f
#define WREG_F  25.0f

#define NB      512                     // sym blocks: 2 per CU (32 waves = max)
#define NT      1024
#define NWAVES  (NT / 64)

#define PACK_BLOCKS 2048
#define PACKED_BYTES ((size_t)BATCH * GCELLS * 2)    // 4 MiB (u16/cell)

typedef float          f4 __attribute__((ext_vector_type(4)));
typedef unsigned int   u32;
typedef unsigned short u16;
typedef u32            u4 __attribute__((ext_vector_type(4)));
typedef u32            u2 __attribute__((ext_vector_type(2)));

// ---------------------------------------------------------------------------
// helpers
// ---------------------------------------------------------------------------
__device__ __forceinline__ u32 quant_cell4(float x, float y, float z, float v) {
    // 4-bit each: u = round_half_up((c+0.5)*15) = floor(c*15 + 8); v: round(v*15)
    const u32 ux = (u32)fmaf(x, 15.0f, 8.0f);
    const u32 uy = (u32)fmaf(y, 15.0f, 8.0f);
    const u32 uz = (u32)fmaf(z, 15.0f, 8.0f);
    const u32 uv = (u32)fmaf(v, 15.0f, 0.5f);
    return ux | (uy << 4) | (uz << 8) | (uv << 12);
}

__device__ __forceinline__ float reg_term(const float* __restrict__ planes, int b) {
    float nv[3][3];
    #pragma unroll
    for (int p = 0; p < NPLANES; ++p) {
        const float nxv = planes[((p * BATCH + b) << 2) + 0];
        const float nyv = planes[((p * BATCH + b) << 2) + 1];
        const float nzv = planes[((p * BATCH + b) << 2) + 2];
        float nrm = fmaxf(sqrtf(nxv*nxv + nyv*nyv + nzv*nzv), 1e-12f);
        nv[p][0] = nxv / nrm; nv[p][1] = nyv / nrm; nv[p][2] = nzv / nrm;
    }
    float r = 0.0f;
    #pragma unroll
    for (int i = 0; i < 3; ++i)
        #pragma unroll
        for (int j = 0; j < 3; ++j) {
            const float m = nv[i][j] * nv[j][i] - (i == j ? 1.0f : 0.0f);
            r += m * m;
        }
    return r;
}

// ---------------------------------------------------------------------------
// Kernel 1: quantize (aux.xyz, vox) -> u16 table (4 bits/field), XCD-swizzled.
// Block 0 initializes out[0] with the regularizer (ordered before sym by the
// kernel boundary; rewritten every replay).
// ---------------------------------------------------------------------------
__device__ __forceinline__ int swizzle_chunk(int bid) {
    return (bid & 7) * (PACK_BLOCKS / 8) + (bid >> 3);
}

__global__ __launch_bounds__(256) void pack_u16_kernel(
    const float* __restrict__ aux,
    const float* __restrict__ vox,
    const float* __restrict__ planes,
    u16* __restrict__ packed,
    float* __restrict__ out)
{
    if (blockIdx.x == 0) {
        __shared__ float rsum[1];
        if (threadIdx.x == 0) rsum[0] = 0.0f;
        __syncthreads();
        if (threadIdx.x < 64) {
            float r = reg_term(planes, threadIdx.x) * (WREG_F / (float)BATCH);
            #pragma unroll
            for (int off = 32; off > 0; off >>= 1)
                r += __shfl_down(r, off);
            if (threadIdx.x == 0) rsum[0] = r;
        }
        __syncthreads();
        if (threadIdx.x == 0) out[0] = rsum[0];
    }

    const int chunk = swizzle_chunk(blockIdx.x);
    const int i = chunk * 256 + threadIdx.x;        // group of 4 cells

    const f4* a4 = (const f4*)aux + (size_t)i * 3;
    const f4 a = a4[0];
    const f4 b = a4[1];
    const f4 c = a4[2];
    const f4 v = ((const f4*)vox)[i];

    const u32 c0 = quant_cell4(a.x, a.y, a.z, v.x);
    const u32 c1 = quant_cell4(a.w, b.x, b.y, v.y);
    const u32 c2 = quant_cell4(b.z, b.w, c.x, v.z);
    const u32 c3 = quant_cell4(c.y, c.z, c.w, v.w);

    u2 o;
    o[0] = c0 | (c1 << 16);
    o[1] = c2 | (c3 << 16);
    *((u2*)packed + i) = o;            // 8-B store: table stays in this L2
}

// ---------------------------------------------------------------------------
// Kernel 2: 512 blocks (2/CU = 32 waves/CU, HW max), 64 KB LDS table staged
// conflict-free (dword load + b32 LDS write, 4 B/lane stride), 4 pts/thread,
// compiler-interleaved gather. One fp32 atomicAdd per block into out[0].
// ---------------------------------------------------------------------------
__global__ __launch_bounds__(NT, 8) void sym_lds_kernel(
    const float* __restrict__ pc,      // (B, N, 3)
    const u16* __restrict__ packed,    // (B*G) u16
    const float* __restrict__ planes,  // (3, B, 4)
    float* __restrict__ out)
{
    __shared__ u16   tab[GCELLS];      // 64 KiB
    __shared__ float wsum[NWAVES];

    const int t    = threadIdx.x;
    const int blk  = blockIdx.x;
    const int xcd  = blk & 7;
    const int slot = blk >> 3;                 // 0..63 on this XCD
    const int b    = xcd * 8 + (slot >> 3);    // batch (8 blocks/batch, same XCD)
    const int c    = slot & 7;                 // eighth of the batch's points

    // ---- pc loads first: latency hides under table staging ----
    const f4* pc4 = (const f4*)pc
                  + (((size_t)(b * NPTS + c * 4096) * 3) >> 2)
                  + (size_t)t * 3;
    f4 A[3];
    #pragma unroll
    for (int i = 0; i < 3; ++i) A[i] = pc4[i];

    // ---- stage 64 KB table: 16 x (dword load + b32 LDS write), 4 B/lane
    //      stride -> consecutive banks -> conflict-free ----
    const u32* gt32  = (const u32*)packed + (size_t)b * (GCELLS / 2);
    u32*       tab32 = (u32*)tab;
    #pragma unroll
    for (int i = 0; i < 16; ++i) {
        const int k = i * NT + t;
        tab32[k] = gt32[k];
    }

    // ---- block-uniform plane constants (sc folded into normals) ----
    float nx[3], ny[3], nz[3], dd[3], mx[3], my[3], mz[3];
    #pragma unroll
    for (int pl = 0; pl < NPLANES; ++pl) {
        const float* P = planes + ((pl * BATCH + b) << 2);
        nx[pl] = P[0]; ny[pl] = P[1]; nz[pl] = P[2]; dd[pl] = P[3];
        const float sc = 2.0f / (nx[pl]*nx[pl] + ny[pl]*ny[pl] + nz[pl]*nz[pl]);
        mx[pl] = sc * nx[pl]; my[pl] = sc * ny[pl]; mz[pl] = sc * nz[pl];
    }

    __syncthreads();

    const float* f = (const float*)A;
    const float SHIFT = 0.5f + EPS_PD;         // fold +0.5 and +eps into q
    const float IOFF  = -32.0f * EPS_PD;       // undo eps in the index path
    const float INV15 = 1.0f / 15.0f;

    // ---- gather loop: 4 points x 3 planes, compiler-interleaved ----
    float acc = 0.0f;
    #pragma unroll
    for (int p = 0; p < 4; ++p) {
        const float px = f[3*p], py = f[3*p+1], pz = f[3*p+2];
        const float pxs = px + SHIFT, pys = py + SHIFT, pzs = pz + SHIFT;
        #pragma unroll
        for (int pl = 0; pl < NPLANES; ++pl) {
            // tt' = dot(p,n) + d  (3 fma); q = p - tt' * (sc*n)
            const float tt  = fmaf(pz, nz[pl], fmaf(py, ny[pl],
                              fmaf(px, nx[pl], dd[pl])));
            const float qxs = fmaf(-tt, mx[pl], pxs);   // qx + 0.5 + eps
            const float qys = fmaf(-tt, my[pl], pys);
            const float qzs = fmaf(-tt, mz[pl], pzs);
            int ix = (int)fmaf(qxs, 32.0f, IOFF);
            int iy = (int)fmaf(qys, 32.0f, IOFF);
            int iz = (int)fmaf(qzs, 32.0f, IOFF);
            ix = min(max(ix, 0), RES - 1);
            iy = min(max(iy, 0), RES - 1);
            iz = min(max(iz, 0), RES - 1);
            const u32 g    = ((u32)ix << 10) + ((u32)iy << 5) + (u32)iz;
            const u32 cell = (u32)tab[g];
            const float dx = fmaf((float)(cell & 15u),        -INV15, qxs);
            const float dy = fmaf((float)((cell >> 4) & 15u), -INV15, qys);
            const float dz = fmaf((float)((cell >> 8) & 15u), -INV15, qzs);
            const float w  = fmaf((float)(cell >> 12),        -INV15, 1.0f);
            acc = fmaf(__builtin_amdgcn_sqrtf(dx*dx + dy*dy + dz*dz), w, acc);
        }
    }

    // ---- block reduce, then one atomicAdd into out[0] ----
    #pragma unroll
    for (int off = 32; off > 0; off >>= 1)
        acc += __shfl_down(acc, off);
    if ((t & 63) == 0) wsum[t >> 6] = acc;
    __syncthreads();
    if (t == 0) {
        float s = 0.0f;
        #pragma unroll
        for (int w = 0; w < NWAVES; ++w) s += wsum[w];
        atomicAdd(out, s * (1.0f / (float)BATCH));
    }
}

// ---------------------------------------------------------------------------
// Fallback (ws too small): direct fp32 gathers + separate finalize.
// ---------------------------------------------------------------------------
__global__ __launch_bounds__(256) void finalize_fb_kernel(
    const float* __restrict__ part, int n_part,
    const float* __restrict__ planes,
    float* __restrict__ out)
{
    __shared__ float sdata[256];

    float s = 0.0f;
    for (int i = threadIdx.x; i < n_part; i += 256)
        s += part[i];

    float r = 0.0f;
    if (threadIdx.x < BATCH)
        r = reg_term(planes, threadIdx.x);

    float val = s * (1.0f / (float)BATCH) + r * (WREG_F / (float)BATCH);

    sdata[threadIdx.x] = val;
    __syncthreads();
    #pragma unroll
    for (int off = 128; off > 0; off >>= 1) {
        if (threadIdx.x < off) sdata[threadIdx.x] += sdata[threadIdx.x + off];
        __syncthreads();
    }
    if (threadIdx.x == 0) out[0] = sdata[0];
}

__global__ __launch_bounds__(256) void sym_fallback_kernel(
    const float* __restrict__ pc,
    const float* __restrict__ aux,
    const float* __restrict__ vox,
    const float* __restrict__ planes,
    float* __restrict__ part)
{
    const int chunk = swizzle_chunk(blockIdx.x);
    const int b  = chunk >> 5;
    const int cb = chunk & 31;

    float nx[3], ny[3], nz[3], dd[3], sc[3];
    #pragma unroll
    for (int pl = 0; pl < NPLANES; ++pl) {
        const float* P = planes + ((pl * BATCH + b) << 2);
        nx[pl] = P[0]; ny[pl] = P[1]; nz[pl] = P[2]; dd[pl] = P[3];
        sc[pl] = 2.0f / (nx[pl]*nx[pl] + ny[pl]*ny[pl] + nz[pl]*nz[pl]);
    }

    const int p0 = b * NPTS + cb * 1024 + threadIdx.x * 4;
    const f4* pc4 = (const f4*)pc + (size_t)(p0 >> 2) * 3;
    const f4 A  = pc4[0];
    const f4 Bv = pc4[1];
    const f4 C  = pc4[2];

    const float px[4] = {A.x, A.w, Bv.z, C.y};
    const float py[4] = {A.y, Bv.x, Bv.w, C.z};
    const float pz[4] = {A.z, Bv.y, C.x, C.w};

    float acc = 0.0f;
    #pragma unroll
    for (int pt = 0; pt < 4; ++pt) {
        #pragma unroll
        for (int pl = 0; pl < NPLANES; ++pl) {
            const float tt = (px[pt]*nx[pl] + py[pt]*ny[pl] + pz[pt]*nz[pl]
                              + dd[pl]) * sc[pl];
            const float qx = px[pt] - tt * nx[pl];
            const float qy = py[pt] - tt * ny[pl];
            const float qz = pz[pt] - tt * nz[pl];
            int ix = (int)((qx + 0.5f) * (float)RES);
            int iy = (int)((qy + 0.5f) * (float)RES);
            int iz = (int)((qz + 0.5f) * (float)RES);
            ix = min(RES - 1, max(0, ix));
            iy = min(RES - 1, max(0, iy));
            iz = min(RES - 1, max(0, iz));
            const int gi = b * GCELLS + (ix << 10) + (iy << 5) + iz;
            const float v  = vox[gi];
            const float dx = qx - aux[gi*3+0] + EPS_PD;
            const float dy = qy - aux[gi*3+1] + EPS_PD;
            const float dz = qz - aux[gi*3+2] + EPS_PD;
            acc += sqrtf(dx*dx + dy*dy + dz*dz) * (1.0f - v);
        }
    }

    #pragma unroll
    for (int off = 32; off > 0; off >>= 1)
        acc += __shfl_down(acc, off);

    __shared__ float ws[4];
    if ((threadIdx.x & 63) == 0) ws[threadIdx.x >> 6] = acc;
    __syncthreads();
    if (threadIdx.x == 0)
        part[blockIdx.x] = ws[0] + ws[1] + ws[2] + ws[3];
}

// ---------------------------------------------------------------------------
extern "C" void kernel_launch(void* const* d_in, const int* in_sizes, int n_in,
                              void* d_out, int out_size, void* d_ws, size_t ws_size,
                              hipStream_t stream)
{
    const float* pc     = (const float*)d_in[0];
    const float* aux    = (const float*)d_in[1];
    const float* vox    = (const float*)d_in[2];
    const float* planes = (const float*)d_in[3];
    float* out = (float*)d_out;

    if (ws_size >= PACKED_BYTES) {
        u16* packed = (u16*)d_ws;
        pack_u16_kernel<<<PACK_BLOCKS, 256, 0, stream>>>(aux, vox, planes, packed, out);
        sym_lds_kernel<<<NB, NT, 0, stream>>>(pc, packed, planes, out);
    } else {
        float* part = (float*)d_ws;
        sym_fallback_kernel<<<PACK_BLOCKS, 256, 0, stream>>>(pc, aux, vox, planes, part);
        finalize_fb_kernel<<<1, 256, 0, stream>>>(part, PACK_BLOCKS, planes, out);
    }
}